// Round 25
// baseline (1241.529 us; speedup 1.0000x reference)
//
#include <hip/hip_runtime.h>

#define H 181
#define T_LEN 1024
#define BB 2             // R32: 2 batch rows per block
#define NBLK 512         // 512 * 2 = 1024; TWO blocks per CU by HW arithmetic
#define NTHR 768         // 12 waves per block; 24 waves/CU at 2 blocks
#define KT3 3            // k-tiles of 64 -> 192 >= 181
#define FRAGB 1024       // bytes per kt fragment (64 lanes x 16 B)
#define PST 192          // unit stride (wsc, FC)
#define XSTR 1027        // x_s stride (odd -> broadcast reads conflict-free)

typedef __attribute__((ext_vector_type(4))) int intx4;

#define LOG2E 1.4426950408889634f
// Schraudolph exp2 (balanced sawtooth, |rel err| <= ~3%), clamped
#define SCH_C  1064992506.0f
#define SCH_LO 897220352.0f
#define SCH_HI 1182433024.0f

__device__ __forceinline__ float exp2_fast(float g) {
    float s = fmaf(g, 8388608.0f, SCH_C);
    s = fminf(fmaxf(s, SCH_LO), SCH_HI);
    return __uint_as_float((unsigned)s);
}
__device__ __forceinline__ float rcpf(float x)   { return __builtin_amdgcn_rcpf(x); }
__device__ __forceinline__ float exp2hw(float x) { return __builtin_amdgcn_exp2f(x); }

// R32: R31 + amdgpu_num_vgpr(80). R31 post-mortem: dur 1235, VGPR 84,
// occupancy STUCK at 35% -> 2nd block never resident; 512 blocks ran as 2
// sequential passes (~2x R26). Root cause: HW VGPR allocation granularity
// rounds 84->88; 24 waves x 88 = 2112 > 2048 pool -> 1 block/CU. R30 (VGPR
// 40) DID fit 2 blocks (occupancy 60) -> boundary = VGPR <= 80 (24x80=1920).
// Fix: cap regalloc at exactly 80 via the dedicated attribute (NOT
// waves_per_eu, whose nonlinear behavior crushed R30 to 40 regs). 84->80
// spills ~4-12 temps incrementally -- nothing like R30's crush. All else
// byte-identical to R31 (passed correctness, absmax 0.0078125).
// Adjudication: VGPR 80 + occ ~70 + dur 450-560 = TLP confirmed;
// VGPR 80 + occ ~70 + dur 660-900 = L2 thrash from 2x scratch WS -> move
// afr to LDS next; occ 35 = granularity > 8 -> try 64 or abandon TLP;
// dur > 1000 = spill cascade -> revert R26.
__device__ __forceinline__ float row_scale(const float* wrow, bool mv) {
    float rm = 0.0f;
    if (mv) for (int k = 0; k < H; ++k) rm = fmaxf(rm, fabsf(wrow[k]));
    return (rm > 1e-30f) ? rm * (1.0f / 127.0f) : 1.0f;
}

__device__ __forceinline__ intx4 build_frag(const float* wrow, float invs,
                                            bool mv, int kt, int q) {
    intx4 frag;
    #pragma unroll
    for (int w = 0; w < 4; ++w) {
        int dw = 0;
        #pragma unroll
        for (int e = 0; e < 4; ++e) {
            int k = kt * 64 + q * 16 + w * 4 + e;
            float v = (mv && k < H) ? wrow[k] * invs : 0.0f;
            v = fminf(fmaxf(rintf(v), -127.0f), 127.0f);
            int iv = (int)v;
            dw |= (iv & 255) << (8 * e);
        }
        frag[w] = dw;
    }
    return frag;
}

__attribute__((amdgpu_num_vgpr(80)))
__launch_bounds__(NTHR, 3)
__global__ void gru_i8(const float* __restrict__ x,
                       const float* __restrict__ w_ih,
                       const float* __restrict__ w_hh,
                       const float* __restrict__ b_ih,
                       const float* __restrict__ b_hh,
                       const float* __restrict__ w_fc,
                       const float* __restrict__ b_fc,
                       float* __restrict__ out) {
    __shared__ __align__(16) char  hfr_s[2 * KT3 * FRAGB];  // 6 KB i8 h dbuf
    __shared__ __align__(16) float x_s[BB * XSTR];          // 8 KB x; reused for FC
    __shared__ float wsc_s[3 * PST];                        // w_hh row scales
    // NO pad: ~17 KB/block; VGPR<=80 -> 24 waves x 80 = 1920 <= 2048 -> 2 blocks/CU

    const int tid  = threadIdx.x;
    const int jt   = tid >> 6;          // wave = unit tile 0..11
    const int lane = tid & 63;
    const int col  = lane & 15;
    const int q    = lane >> 4;
    const int b0   = blockIdx.x * BB;

    // ---- A fragments: per-row int8 w_hh, 3 gates x 3 kt, 9 NAMED regs ----
    const int  mu = jt * 16 + col;
    const bool mv = (mu < H);
    const float* wrowR = w_hh + (size_t)(0 * H + (mv ? mu : 0)) * H;
    const float* wrowZ = w_hh + (size_t)(1 * H + (mv ? mu : 0)) * H;
    const float* wrowN = w_hh + (size_t)(2 * H + (mv ? mu : 0)) * H;
    const float sR = row_scale(wrowR, mv);
    const float sZ = row_scale(wrowZ, mv);
    const float sN = row_scale(wrowN, mv);
    const float iR = 1.0f / sR, iZ = 1.0f / sZ, iN = 1.0f / sN;
    const intx4 afR0 = build_frag(wrowR, iR, mv, 0, q);
    const intx4 afR1 = build_frag(wrowR, iR, mv, 1, q);
    const intx4 afR2 = build_frag(wrowR, iR, mv, 2, q);
    const intx4 afZ0 = build_frag(wrowZ, iZ, mv, 0, q);
    const intx4 afZ1 = build_frag(wrowZ, iZ, mv, 1, q);
    const intx4 afZ2 = build_frag(wrowZ, iZ, mv, 2, q);
    const intx4 afN0 = build_frag(wrowN, iN, mv, 0, q);
    const intx4 afN1 = build_frag(wrowN, iN, mv, 1, q);
    const intx4 afN2 = build_frag(wrowN, iN, mv, 2, q);
    if (q == 0) {
        wsc_s[0 * PST + mu] = sR;
        wsc_s[1 * PST + mu] = sZ;
        wsc_s[2 * PST + mu] = sN;
    }

    // ---- stage x (stride 1027); zero h frag buffers ----
    for (int i = tid; i < BB * T_LEN; i += NTHR) {
        int bb = i >> 10, t = i & 1023;
        x_s[bb * XSTR + t] = x[(size_t)b0 * T_LEN + i];
    }
    {
        int* hz = (int*)hfr_s;
        for (int i = tid; i < 2 * KT3 * FRAGB / 4; i += NTHR) hz[i] = 0;
    }
    __syncthreads();   // wsc_s ready (full barrier; prologue only)

    // ---- dense per-lane identity after DPP redistribute ----
    const int  rr4 = (col >> 2) & 3;       // reg index this lane receives
    const int  b   = col & 3;              // fragment col 0..3 (2..3 = dup)
    const int  bx  = col & 1;              // real batch index 0..1
    const int  u   = jt * 16 + q * 4 + rr4;  // unit
    const bool jv  = (u < H);
    const float dqR = -LOG2E * wsc_s[0 * PST + u] * (1.0f / 127.0f);
    const float dqZ = -LOG2E * wsc_s[1 * PST + u] * (1.0f / 127.0f);
    const float dqN =  2.0f * LOG2E * wsc_s[2 * PST + u] * (1.0f / 127.0f);
    const float baseR = jv ? -LOG2E * (b_ih[u] + b_hh[u])             : 0.0f;
    const float baseZ = jv ? -LOG2E * (b_ih[H + u] + b_hh[H + u])     : 0.0f;
    const float baseN = jv ?  2.0f * LOG2E * b_hh[2 * H + u]          : 0.0f;
    const float wrS = jv ? -LOG2E * w_ih[u]                : 0.0f;
    const float wzS = jv ? -LOG2E * w_ih[H + u]            : 0.0f;
    const float wnS = jv ?  2.0f * LOG2E * w_ih[2 * H + u] : 0.0f;
    const float bnI = jv ?  2.0f * LOG2E * b_ih[2 * H + u] : 0.0f;
    // per-lane byte slot in the fragment layout (this lane's unit u, col b)
    const int wboff8 = (jt >> 2) * FRAGB + (((jt & 3) * 16 + b) * 16) + q * 4 + rr4;
    const int rbase = lane * 16;

    float h = 0.0f;

// LDS-only barrier: ds_write_b8 visibility needs lgkmcnt(0)+s_barrier only;
// scratch spill traffic (vmcnt) is lane-private and floats across steps.
#define LDS_BARRIER() do {                                                    \
    __builtin_amdgcn_sched_barrier(0);                                        \
    asm volatile("s_waitcnt lgkmcnt(0)" ::: "memory");                        \
    __builtin_amdgcn_s_barrier();                                             \
    __builtin_amdgcn_sched_barrier(0);                                        \
} while (0)

// One GRU step: macro (no lambda -> nothing address-taken).
#define STEP(rb, wb, t_) do {                                                 \
    intx4 bf0 = *(const intx4*)((rb) + 0 * FRAGB + rbase);                    \
    intx4 bf1 = *(const intx4*)((rb) + 1 * FRAGB + rbase);                    \
    intx4 bf2 = *(const intx4*)((rb) + 2 * FRAGB + rbase);                    \
    intx4 aR = {0,0,0,0}, aZ = {0,0,0,0}, aN = {0,0,0,0};                     \
    aR = __builtin_amdgcn_mfma_i32_16x16x64_i8(afR0, bf0, aR, 0, 0, 0);       \
    aZ = __builtin_amdgcn_mfma_i32_16x16x64_i8(afZ0, bf0, aZ, 0, 0, 0);       \
    aN = __builtin_amdgcn_mfma_i32_16x16x64_i8(afN0, bf0, aN, 0, 0, 0);       \
    aR = __builtin_amdgcn_mfma_i32_16x16x64_i8(afR1, bf1, aR, 0, 0, 0);       \
    aZ = __builtin_amdgcn_mfma_i32_16x16x64_i8(afZ1, bf1, aZ, 0, 0, 0);       \
    aN = __builtin_amdgcn_mfma_i32_16x16x64_i8(afN1, bf1, aN, 0, 0, 0);       \
    aR = __builtin_amdgcn_mfma_i32_16x16x64_i8(afR2, bf2, aR, 0, 0, 0);       \
    aZ = __builtin_amdgcn_mfma_i32_16x16x64_i8(afZ2, bf2, aZ, 0, 0, 0);       \
    aN = __builtin_amdgcn_mfma_i32_16x16x64_i8(afN2, bf2, aN, 0, 0, 0);       \
    int vR = aR[0], vZ = aZ[0], vN = aN[0];                                   \
    vR = __builtin_amdgcn_update_dpp(vR, aR[1], 0x114, 0xF, 0x2, false);      \
    vR = __builtin_amdgcn_update_dpp(vR, aR[2], 0x118, 0xF, 0x4, false);      \
    vR = __builtin_amdgcn_update_dpp(vR, aR[3], 0x11C, 0xF, 0x8, false);      \
    vZ = __builtin_amdgcn_update_dpp(vZ, aZ[1], 0x114, 0xF, 0x2, false);      \
    vZ = __builtin_amdgcn_update_dpp(vZ, aZ[2], 0x118, 0xF, 0x4, false);      \
    vZ = __builtin_amdgcn_update_dpp(vZ, aZ[3], 0x11C, 0xF, 0x8, false);      \
    vN = __builtin_amdgcn_update_dpp(vN, aN[1], 0x114, 0xF, 0x2, false);      \
    vN = __builtin_amdgcn_update_dpp(vN, aN[2], 0x118, 0xF, 0x4, false);      \
    vN = __builtin_amdgcn_update_dpp(vN, aN[3], 0x11C, 0xF, 0x8, false);      \
    float pR = fmaf((float)vR, dqR, baseR);                                   \
    float pZ = fmaf((float)vZ, dqZ, baseZ);                                   \
    float pN = fmaf((float)vN, dqN, baseN);                                   \
    float xv = x_s[bx * XSTR + (t_)];                                         \
    float er = exp2_fast(fmaf(xv, wrS, pR));                                  \
    float ez = exp2hw(fminf(fmaf(xv, wzS, pZ), 14.0f));                       \
    float dR = 1.0f + er, dZ = 1.0f + ez;                                     \
    float qq = rcpf(dR * dZ);                                                 \
    float rr = qq * dZ, zz = qq * dR;                                         \
    float gn = fmaf(rr, pN, fmaf(xv, wnS, bnI));                              \
    float en = exp2hw(fminf(gn, 30.0f));                                      \
    float nn = fmaf(-2.0f, rcpf(1.0f + en), 1.0f);                            \
    h = fmaf(zz, h - nn, nn);                                                 \
    int hq = __float_as_int(fmaf(h, 127.0f, 12582912.0f));                    \
    *(char*)((wb) + wboff8) = (char)hq;                                       \
    LDS_BARRIER();                                                            \
} while (0)

    char* buf0 = hfr_s;
    char* buf1 = hfr_s + KT3 * FRAGB;
    for (int t = 0; t < T_LEN; t += 2) {
        STEP(buf0, buf1, t);
        STEP(buf1, buf0, t + 1);
    }
#undef STEP
#undef LDS_BARRIER

    // ---- final FC: publish h (f32) into x_s (x done), 20 lanes reduce ----
    __syncthreads();
    // b in {0,1} publish real h; b in {2,3} publish duplicates to unread
    // slots (b*PST+u <= 3*192+191 = 767 < BB*XSTR = 2054, in bounds).
    if (u < PST) x_s[b * PST + u] = h;
    __syncthreads();
    if (tid < BB * 10) {
        int bb = tid / 10, c = tid % 10;
        float acc = b_fc[c];
        for (int k = 0; k < H; ++k)
            acc = fmaf(x_s[bb * PST + k], w_fc[c * H + k], acc);
        out[(b0 + bb) * 10 + c] = acc;
    }
}

extern "C" void kernel_launch(void* const* d_in, const int* in_sizes, int n_in,
                              void* d_out, int out_size, void* d_ws, size_t ws_size,
                              hipStream_t stream) {
    const float* x    = (const float*)d_in[0];
    const float* w_ih = (const float*)d_in[1];
    const float* w_hh = (const float*)d_in[2];
    const float* b_ih = (const float*)d_in[3];
    const float* b_hh = (const float*)d_in[4];
    const float* w_fc = (const float*)d_in[5];
    const float* b_fc = (const float*)d_in[6];
    float* out = (float*)d_out;

    gru_i8<<<NBLK, NTHR, 0, stream>>>(x, w_ih, w_hh, b_ih, b_hh, w_fc, b_fc, out);
}

// Round 26
// 1096.127 us; speedup vs baseline: 1.1327x; 1.1327x over previous
//
#include <hip/hip_runtime.h>

#define H 181
#define T_LEN 1024
#define BB 4             // batch rows per block
#define NBLK 256         // 256 * 4 = 1024; one block per CU (LDS-pinned: 135KB)
#define NTHR 768         // 12 waves, 3 per SIMD (measured-best structure)
#define KT3 3            // k-tiles of 64 -> 192 >= 181
#define FRAGB 1024       // bytes per kt fragment (64 lanes x 16 B)
#define PST 192          // unit stride (wsc, FC)
#define XSTR 1027        // x_s stride (odd -> broadcast reads conflict-free)

typedef __attribute__((ext_vector_type(4))) int intx4;

#define LOG2E 1.4426950408889634f
// Schraudolph exp2 (balanced sawtooth, |rel err| <= ~3%), clamped
#define SCH_C  1064992506.0f
#define SCH_LO 897220352.0f
#define SCH_HI 1182433024.0f

__device__ __forceinline__ float exp2_fast(float g) {
    float s = fmaf(g, 8388608.0f, SCH_C);
    s = fminf(fmaxf(s, SCH_LO), SCH_HI);
    return __uint_as_float((unsigned)s);
}
__device__ __forceinline__ float rcpf(float x)   { return __builtin_amdgcn_rcpf(x); }
__device__ __forceinline__ float exp2hw(float x) { return __builtin_amdgcn_exp2f(x); }

// R33: R26 base (657.8us best) + afr moved to LDS BY CONSTRUCTION.
// R32 post-mortem: VGPR 80 + occupancy still 35% -> waves/SIMD quantized in
// power-of-2 bands (m69: 8@<=64, 4@<=128); 6/SIMD unreachable at 80. Also
// re-derived: BB=2 TLP gain was capped ~8-9% (per-block work doesn't shrink
// with BB) -> TLP arc abandoned. Remaining unexonerated term: per-step spill
// RELOADS traverse L2 (~200-225cy) + 64-bit scratch addressing VALU. The
// allocator won 4 de-spill fights, so stop fighting: put afr in LDS
// explicitly. 12 waves x 9 frags x 1KB = 108KB (LDS total 135KB < 160KB;
// also pins 1 block/CU, pad no longer needed). Each lane reads only its own
// 144B/step: 9 ds_read_b128 at the proven lane*16 conflict-free pattern
// (~12cy; DS pipe 36x12=432cy/SIMD < MFMA 551cy -> hidden). volatile reads
// prevent LICM from hoisting loads back to regs (would recreate the spill).
// int values pass through LDS bit-exactly -> numerics bit-identical.
// Adjudication: VGPR 56-76 + WRITE ~40KB + dur 560-615 = L2-latency cut
// real; dur ~658 flat = scratch path fully free -> structural plateau;
// dur > 680 = volatile ordering overhead -> revert R26.
__device__ __forceinline__ float row_scale(const float* wrow, bool mv) {
    float rm = 0.0f;
    if (mv) for (int k = 0; k < H; ++k) rm = fmaxf(rm, fabsf(wrow[k]));
    return (rm > 1e-30f) ? rm * (1.0f / 127.0f) : 1.0f;
}

__device__ __forceinline__ intx4 build_frag(const float* wrow, float invs,
                                            bool mv, int kt, int q) {
    intx4 frag;
    #pragma unroll
    for (int w = 0; w < 4; ++w) {
        int dw = 0;
        #pragma unroll
        for (int e = 0; e < 4; ++e) {
            int k = kt * 64 + q * 16 + w * 4 + e;
            float v = (mv && k < H) ? wrow[k] * invs : 0.0f;
            v = fminf(fmaxf(rintf(v), -127.0f), 127.0f);
            int iv = (int)v;
            dw |= (iv & 255) << (8 * e);
        }
        frag[w] = dw;
    }
    return frag;
}

__launch_bounds__(NTHR, 3)
__global__ void gru_i8(const float* __restrict__ x,
                       const float* __restrict__ w_ih,
                       const float* __restrict__ w_hh,
                       const float* __restrict__ b_ih,
                       const float* __restrict__ b_hh,
                       const float* __restrict__ w_fc,
                       const float* __restrict__ b_fc,
                       float* __restrict__ out) {
    __shared__ __align__(16) char  hfr_s[2 * KT3 * FRAGB];   // 6 KB i8 h dbuf
    __shared__ __align__(16) char  afr_s[12 * 9 * FRAGB];    // 108 KB weights
    __shared__ __align__(16) float x_s[BB * XSTR];           // 16 KB x; FC reuse
    __shared__ float wsc_s[3 * PST];                         // w_hh row scales
    // total ~135 KB -> 1 block/CU by LDS alone (pad removed)

    const int tid  = threadIdx.x;
    const int jt   = tid >> 6;          // wave = unit tile 0..11
    const int lane = tid & 63;
    const int col  = lane & 15;
    const int q    = lane >> 4;
    const int b0   = blockIdx.x * BB;

    // ---- A fragments: per-row int8 w_hh, 3 gates x 3 kt -> LDS ----
    const int  mu = jt * 16 + col;
    const bool mv = (mu < H);
    const float* wrowR = w_hh + (size_t)(0 * H + (mv ? mu : 0)) * H;
    const float* wrowZ = w_hh + (size_t)(1 * H + (mv ? mu : 0)) * H;
    const float* wrowN = w_hh + (size_t)(2 * H + (mv ? mu : 0)) * H;
    const float sR = row_scale(wrowR, mv);
    const float sZ = row_scale(wrowZ, mv);
    const float sN = row_scale(wrowN, mv);
    const float iR = 1.0f / sR, iZ = 1.0f / sZ, iN = 1.0f / sN;
    // per-lane base into afr_s: wave jt, frag f at abase + f*FRAGB
    const int abase = jt * 9 * FRAGB + lane * 16;
    *(intx4*)(afr_s + abase + 0 * FRAGB) = build_frag(wrowR, iR, mv, 0, q);
    *(intx4*)(afr_s + abase + 1 * FRAGB) = build_frag(wrowR, iR, mv, 1, q);
    *(intx4*)(afr_s + abase + 2 * FRAGB) = build_frag(wrowR, iR, mv, 2, q);
    *(intx4*)(afr_s + abase + 3 * FRAGB) = build_frag(wrowZ, iZ, mv, 0, q);
    *(intx4*)(afr_s + abase + 4 * FRAGB) = build_frag(wrowZ, iZ, mv, 1, q);
    *(intx4*)(afr_s + abase + 5 * FRAGB) = build_frag(wrowZ, iZ, mv, 2, q);
    *(intx4*)(afr_s + abase + 6 * FRAGB) = build_frag(wrowN, iN, mv, 0, q);
    *(intx4*)(afr_s + abase + 7 * FRAGB) = build_frag(wrowN, iN, mv, 1, q);
    *(intx4*)(afr_s + abase + 8 * FRAGB) = build_frag(wrowN, iN, mv, 2, q);
    if (q == 0) {
        wsc_s[0 * PST + mu] = sR;
        wsc_s[1 * PST + mu] = sZ;
        wsc_s[2 * PST + mu] = sN;
    }

    // ---- stage x (stride 1027); zero h frag buffers ----
    for (int i = tid; i < BB * T_LEN; i += NTHR) {
        int bb = i >> 10, t = i & 1023;
        x_s[bb * XSTR + t] = x[(size_t)b0 * T_LEN + i];
    }
    {
        int* hz = (int*)hfr_s;
        for (int i = tid; i < 2 * KT3 * FRAGB / 4; i += NTHR) hz[i] = 0;
    }
    __syncthreads();   // wsc_s + afr_s ready (full barrier; prologue only)

    // ---- dense per-lane identity after DPP redistribute ----
    const int  rr4 = (col >> 2) & 3;       // reg index this lane receives
    const int  b   = col & 3;              // batch
    const int  u   = jt * 16 + q * 4 + rr4;  // unit
    const bool jv  = (u < H);
    const float dqR = -LOG2E * wsc_s[0 * PST + u] * (1.0f / 127.0f);
    const float dqZ = -LOG2E * wsc_s[1 * PST + u] * (1.0f / 127.0f);
    const float dqN =  2.0f * LOG2E * wsc_s[2 * PST + u] * (1.0f / 127.0f);
    const float baseR = jv ? -LOG2E * (b_ih[u] + b_hh[u])             : 0.0f;
    const float baseZ = jv ? -LOG2E * (b_ih[H + u] + b_hh[H + u])     : 0.0f;
    const float baseN = jv ?  2.0f * LOG2E * b_hh[2 * H + u]          : 0.0f;
    const float wrS = jv ? -LOG2E * w_ih[u]                : 0.0f;
    const float wzS = jv ? -LOG2E * w_ih[H + u]            : 0.0f;
    const float wnS = jv ?  2.0f * LOG2E * w_ih[2 * H + u] : 0.0f;
    const float bnI = jv ?  2.0f * LOG2E * b_ih[2 * H + u] : 0.0f;
    // per-lane byte slot in the fragment layout (this lane's unit u, batch b)
    const int wboff8 = (jt >> 2) * FRAGB + (((jt & 3) * 16 + b) * 16) + q * 4 + rr4;
    const int rbase = lane * 16;

    float h = 0.0f;

// LDS-only barrier: ds_write_b8 visibility needs lgkmcnt(0)+s_barrier only;
// (no scratch traffic left, but keep the cheap form).
#define LDS_BARRIER() do {                                                    \
    __builtin_amdgcn_sched_barrier(0);                                        \
    asm volatile("s_waitcnt lgkmcnt(0)" ::: "memory");                        \
    __builtin_amdgcn_s_barrier();                                             \
    __builtin_amdgcn_sched_barrier(0);                                        \
} while (0)

// One GRU step. afr frags re-read from LDS every step (volatile blocks
// LICM re-hoist -> no register spill by construction). Same-lane data:
// no barrier needed for afr, only lgkmcnt (compiler-inserted) before use.
#define STEP(rb, wb, t_) do {                                                 \
    intx4 bf0 = *(const intx4*)((rb) + 0 * FRAGB + rbase);                    \
    intx4 bf1 = *(const intx4*)((rb) + 1 * FRAGB + rbase);                    \
    intx4 bf2 = *(const intx4*)((rb) + 2 * FRAGB + rbase);                    \
    intx4 wR0 = *(volatile const intx4*)(afr_s + abase + 0 * FRAGB);          \
    intx4 wZ0 = *(volatile const intx4*)(afr_s + abase + 3 * FRAGB);          \
    intx4 wN0 = *(volatile const intx4*)(afr_s + abase + 6 * FRAGB);          \
    intx4 wR1 = *(volatile const intx4*)(afr_s + abase + 1 * FRAGB);          \
    intx4 wZ1 = *(volatile const intx4*)(afr_s + abase + 4 * FRAGB);          \
    intx4 wN1 = *(volatile const intx4*)(afr_s + abase + 7 * FRAGB);          \
    intx4 wR2 = *(volatile const intx4*)(afr_s + abase + 2 * FRAGB);          \
    intx4 wZ2 = *(volatile const intx4*)(afr_s + abase + 5 * FRAGB);          \
    intx4 wN2 = *(volatile const intx4*)(afr_s + abase + 8 * FRAGB);          \
    intx4 aR = {0,0,0,0}, aZ = {0,0,0,0}, aN = {0,0,0,0};                     \
    aR = __builtin_amdgcn_mfma_i32_16x16x64_i8(wR0, bf0, aR, 0, 0, 0);        \
    aZ = __builtin_amdgcn_mfma_i32_16x16x64_i8(wZ0, bf0, aZ, 0, 0, 0);        \
    aN = __builtin_amdgcn_mfma_i32_16x16x64_i8(wN0, bf0, aN, 0, 0, 0);        \
    aR = __builtin_amdgcn_mfma_i32_16x16x64_i8(wR1, bf1, aR, 0, 0, 0);        \
    aZ = __builtin_amdgcn_mfma_i32_16x16x64_i8(wZ1, bf1, aZ, 0, 0, 0);        \
    aN = __builtin_amdgcn_mfma_i32_16x16x64_i8(wN1, bf1, aN, 0, 0, 0);        \
    aR = __builtin_amdgcn_mfma_i32_16x16x64_i8(wR2, bf2, aR, 0, 0, 0);        \
    aZ = __builtin_amdgcn_mfma_i32_16x16x64_i8(wZ2, bf2, aZ, 0, 0, 0);        \
    aN = __builtin_amdgcn_mfma_i32_16x16x64_i8(wN2, bf2, aN, 0, 0, 0);        \
    int vR = aR[0], vZ = aZ[0], vN = aN[0];                                   \
    vR = __builtin_amdgcn_update_dpp(vR, aR[1], 0x114, 0xF, 0x2, false);      \
    vR = __builtin_amdgcn_update_dpp(vR, aR[2], 0x118, 0xF, 0x4, false);      \
    vR = __builtin_amdgcn_update_dpp(vR, aR[3], 0x11C, 0xF, 0x8, false);      \
    vZ = __builtin_amdgcn_update_dpp(vZ, aZ[1], 0x114, 0xF, 0x2, false);      \
    vZ = __builtin_amdgcn_update_dpp(vZ, aZ[2], 0x118, 0xF, 0x4, false);      \
    vZ = __builtin_amdgcn_update_dpp(vZ, aZ[3], 0x11C, 0xF, 0x8, false);      \
    vN = __builtin_amdgcn_update_dpp(vN, aN[1], 0x114, 0xF, 0x2, false);      \
    vN = __builtin_amdgcn_update_dpp(vN, aN[2], 0x118, 0xF, 0x4, false);      \
    vN = __builtin_amdgcn_update_dpp(vN, aN[3], 0x11C, 0xF, 0x8, false);      \
    float pR = fmaf((float)vR, dqR, baseR);                                   \
    float pZ = fmaf((float)vZ, dqZ, baseZ);                                   \
    float pN = fmaf((float)vN, dqN, baseN);                                   \
    float xv = x_s[b * XSTR + (t_)];                                          \
    float er = exp2_fast(fmaf(xv, wrS, pR));                                  \
    float ez = exp2hw(fminf(fmaf(xv, wzS, pZ), 14.0f));                       \
    float dR = 1.0f + er, dZ = 1.0f + ez;                                     \
    float qq = rcpf(dR * dZ);                                                 \
    float rr = qq * dZ, zz = qq * dR;                                         \
    float gn = fmaf(rr, pN, fmaf(xv, wnS, bnI));                              \
    float en = exp2hw(fminf(gn, 30.0f));                                      \
    float nn = fmaf(-2.0f, rcpf(1.0f + en), 1.0f);                            \
    h = fmaf(zz, h - nn, nn);                                                 \
    int hq = __float_as_int(fmaf(h, 127.0f, 12582912.0f));                    \
    *(char*)((wb) + wboff8) = (char)hq;                                       \
    LDS_BARRIER();                                                            \
} while (0)

    char* buf0 = hfr_s;
    char* buf1 = hfr_s + KT3 * FRAGB;
    for (int t = 0; t < T_LEN; t += 2) {
        STEP(buf0, buf1, t);
        STEP(buf1, buf0, t + 1);
    }
#undef STEP
#undef LDS_BARRIER

    // ---- final FC: publish h (f32) into x_s (x done), 40 lanes reduce ----
    __syncthreads();
    if (u < PST) x_s[b * PST + u] = h;
    __syncthreads();
    if (tid < BB * 10) {
        int bb = tid / 10, c = tid % 10;
        float acc = b_fc[c];
        for (int k = 0; k < H; ++k)
            acc = fmaf(x_s[bb * PST + k], w_fc[c * H + k], acc);
        out[(b0 + bb) * 10 + c] = acc;
    }
}

extern "C" void kernel_launch(void* const* d_in, const int* in_sizes, int n_in,
                              void* d_out, int out_size, void* d_ws, size_t ws_size,
                              hipStream_t stream) {
    const float* x    = (const float*)d_in[0];
    const float* w_ih = (const float*)d_in[1];
    const float* w_hh = (const float*)d_in[2];
    const float* b_ih = (const float*)d_in[3];
    const float* b_hh = (const float*)d_in[4];
    const float* w_fc = (const float*)d_in[5];
    const float* b_fc = (const float*)d_in[6];
    float* out = (float*)d_out;

    gru_i8<<<NBLK, NTHR, 0, stream>>>(x, w_ih, w_hh, b_ih, b_hh, w_fc, b_fc, out);
}

// Round 27
// 652.906 us; speedup vs baseline: 1.9015x; 1.6788x over previous
//
#include <hip/hip_runtime.h>

#define H 181
#define T_LEN 1024
#define BB 4             // batch rows per block
#define NBLK 256         // 256 * 4 = 1024; one block per CU (LDS-pinned)
#define NTHR 768         // 12 waves, 3 per SIMD (measured-best structure)
#define KT3 3            // k-tiles of 64 -> 192 >= 181
#define FRAGB 1024       // bytes per kt fragment (64 lanes x 16 B)
#define PST 192          // unit stride (wsc, FC)
#define XSTR 1027        // x_s stride (odd -> broadcast reads conflict-free)

typedef __attribute__((ext_vector_type(4))) int intx4;

#define LOG2E 1.4426950408889634f
// Schraudolph exp2 (balanced sawtooth, |rel err| <= ~3%), clamped
#define SCH_C  1064992506.0f
#define SCH_LO 897220352.0f
#define SCH_HI 1182433024.0f

__device__ __forceinline__ float exp2_fast(float g) {
    float s = fmaf(g, 8388608.0f, SCH_C);
    s = fminf(fmaxf(s, SCH_LO), SCH_HI);
    return __uint_as_float((unsigned)s);
}
__device__ __forceinline__ float rcpf(float x)   { return __builtin_amdgcn_rcpf(x); }
__device__ __forceinline__ float exp2hw(float x) { return __builtin_amdgcn_exp2f(x); }

// R34 == R26 restore (measured 657.8us, session best). R33 post-mortem:
// afr-in-LDS de-spilled successfully (VGPR 68, WRITE 40KB) but dur 1096us:
// 144 ds_read_b128/CU/step x ~12cy ~= 1730cy saturated the DS pipe. FINAL
// verdict on the spill saga: the compiler's scratch spill was the OPTIMAL
// placement (L2-cached, latency-hidden, off the DS pipe); R20/21/22/23/33
// were all fighting a correct decision. R26's 657.8 is structure-bound
// (barrier-locked serial recurrence: chain latency + issue interleave),
// not throughput-bound: MFMA 29%, VALU 46%, DS ~26%, HBM 0.8%, and every
// attacked term (LDS redundancy R18, spill R20-23/33, drain R26 +2%, VALU
// R27, TLP R30-32) moved <= 2%. Restoring best state verbatim.
__device__ __forceinline__ float row_scale(const float* wrow, bool mv) {
    float rm = 0.0f;
    if (mv) for (int k = 0; k < H; ++k) rm = fmaxf(rm, fabsf(wrow[k]));
    return (rm > 1e-30f) ? rm * (1.0f / 127.0f) : 1.0f;
}

__device__ __forceinline__ intx4 build_frag(const float* wrow, float invs,
                                            bool mv, int kt, int q) {
    intx4 frag;
    #pragma unroll
    for (int w = 0; w < 4; ++w) {
        int dw = 0;
        #pragma unroll
        for (int e = 0; e < 4; ++e) {
            int k = kt * 64 + q * 16 + w * 4 + e;
            float v = (mv && k < H) ? wrow[k] * invs : 0.0f;
            v = fminf(fmaxf(rintf(v), -127.0f), 127.0f);
            int iv = (int)v;
            dw |= (iv & 255) << (8 * e);
        }
        frag[w] = dw;
    }
    return frag;
}

__launch_bounds__(NTHR, 3)
__global__ void gru_i8(const float* __restrict__ x,
                       const float* __restrict__ w_ih,
                       const float* __restrict__ w_hh,
                       const float* __restrict__ b_ih,
                       const float* __restrict__ b_hh,
                       const float* __restrict__ w_fc,
                       const float* __restrict__ b_fc,
                       float* __restrict__ out) {
    __shared__ __align__(16) char  hfr_s[2 * KT3 * FRAGB];  // 6 KB i8 h dbuf
    __shared__ __align__(16) float x_s[BB * XSTR];          // 16 KB x; reused for FC
    __shared__ float wsc_s[3 * PST];                        // w_hh row scales
    __shared__ volatile char pad_s[57344];                  // total > 80 KB: pin 1 block/CU

    const int tid  = threadIdx.x;
    const int jt   = tid >> 6;          // wave = unit tile 0..11
    const int lane = tid & 63;
    const int col  = lane & 15;
    const int q    = lane >> 4;
    const int b0   = blockIdx.x * BB;
    if (tid == 0) pad_s[0] = 0;

    // ---- A fragments: per-row int8 w_hh, 3 gates x 3 kt, 9 NAMED regs ----
    const int  mu = jt * 16 + col;
    const bool mv = (mu < H);
    const float* wrowR = w_hh + (size_t)(0 * H + (mv ? mu : 0)) * H;
    const float* wrowZ = w_hh + (size_t)(1 * H + (mv ? mu : 0)) * H;
    const float* wrowN = w_hh + (size_t)(2 * H + (mv ? mu : 0)) * H;
    const float sR = row_scale(wrowR, mv);
    const float sZ = row_scale(wrowZ, mv);
    const float sN = row_scale(wrowN, mv);
    const float iR = 1.0f / sR, iZ = 1.0f / sZ, iN = 1.0f / sN;
    const intx4 afR0 = build_frag(wrowR, iR, mv, 0, q);
    const intx4 afR1 = build_frag(wrowR, iR, mv, 1, q);
    const intx4 afR2 = build_frag(wrowR, iR, mv, 2, q);
    const intx4 afZ0 = build_frag(wrowZ, iZ, mv, 0, q);
    const intx4 afZ1 = build_frag(wrowZ, iZ, mv, 1, q);
    const intx4 afZ2 = build_frag(wrowZ, iZ, mv, 2, q);
    const intx4 afN0 = build_frag(wrowN, iN, mv, 0, q);
    const intx4 afN1 = build_frag(wrowN, iN, mv, 1, q);
    const intx4 afN2 = build_frag(wrowN, iN, mv, 2, q);
    if (q == 0) {
        wsc_s[0 * PST + mu] = sR;
        wsc_s[1 * PST + mu] = sZ;
        wsc_s[2 * PST + mu] = sN;
    }

    // ---- stage x (stride 1027); zero h frag buffers ----
    for (int i = tid; i < BB * T_LEN; i += NTHR) {
        int bb = i >> 10, t = i & 1023;
        x_s[bb * XSTR + t] = x[(size_t)b0 * T_LEN + i];
    }
    {
        int* hz = (int*)hfr_s;
        for (int i = tid; i < 2 * KT3 * FRAGB / 4; i += NTHR) hz[i] = 0;
    }
    __syncthreads();   // wsc_s ready (full barrier; prologue only)

    // ---- dense per-lane identity after DPP redistribute ----
    const int  rr4 = (col >> 2) & 3;       // reg index this lane receives
    const int  b   = col & 3;              // batch
    const int  u   = jt * 16 + q * 4 + rr4;  // unit
    const bool jv  = (u < H);
    const float dqR = -LOG2E * wsc_s[0 * PST + u] * (1.0f / 127.0f);
    const float dqZ = -LOG2E * wsc_s[1 * PST + u] * (1.0f / 127.0f);
    const float dqN =  2.0f * LOG2E * wsc_s[2 * PST + u] * (1.0f / 127.0f);
    const float baseR = jv ? -LOG2E * (b_ih[u] + b_hh[u])             : 0.0f;
    const float baseZ = jv ? -LOG2E * (b_ih[H + u] + b_hh[H + u])     : 0.0f;
    const float baseN = jv ?  2.0f * LOG2E * b_hh[2 * H + u]          : 0.0f;
    const float wrS = jv ? -LOG2E * w_ih[u]                : 0.0f;
    const float wzS = jv ? -LOG2E * w_ih[H + u]            : 0.0f;
    const float wnS = jv ?  2.0f * LOG2E * w_ih[2 * H + u] : 0.0f;
    const float bnI = jv ?  2.0f * LOG2E * b_ih[2 * H + u] : 0.0f;
    // per-lane byte slot in the fragment layout (this lane's unit u, batch b)
    const int wboff8 = (jt >> 2) * FRAGB + (((jt & 3) * 16 + b) * 16) + q * 4 + rr4;
    const int rbase = lane * 16;

    float h = 0.0f;

// LDS-only barrier: ds_write_b8 visibility needs lgkmcnt(0)+s_barrier only;
// scratch spill traffic (vmcnt) is lane-private and floats across steps.
#define LDS_BARRIER() do {                                                    \
    __builtin_amdgcn_sched_barrier(0);                                        \
    asm volatile("s_waitcnt lgkmcnt(0)" ::: "memory");                        \
    __builtin_amdgcn_s_barrier();                                             \
    __builtin_amdgcn_sched_barrier(0);                                        \
} while (0)

// One GRU step: macro (no lambda -> nothing address-taken).
#define STEP(rb, wb, t_) do {                                                 \
    intx4 bf0 = *(const intx4*)((rb) + 0 * FRAGB + rbase);                    \
    intx4 bf1 = *(const intx4*)((rb) + 1 * FRAGB + rbase);                    \
    intx4 bf2 = *(const intx4*)((rb) + 2 * FRAGB + rbase);                    \
    intx4 aR = {0,0,0,0}, aZ = {0,0,0,0}, aN = {0,0,0,0};                     \
    aR = __builtin_amdgcn_mfma_i32_16x16x64_i8(afR0, bf0, aR, 0, 0, 0);       \
    aZ = __builtin_amdgcn_mfma_i32_16x16x64_i8(afZ0, bf0, aZ, 0, 0, 0);       \
    aN = __builtin_amdgcn_mfma_i32_16x16x64_i8(afN0, bf0, aN, 0, 0, 0);       \
    aR = __builtin_amdgcn_mfma_i32_16x16x64_i8(afR1, bf1, aR, 0, 0, 0);       \
    aZ = __builtin_amdgcn_mfma_i32_16x16x64_i8(afZ1, bf1, aZ, 0, 0, 0);       \
    aN = __builtin_amdgcn_mfma_i32_16x16x64_i8(afN1, bf1, aN, 0, 0, 0);       \
    aR = __builtin_amdgcn_mfma_i32_16x16x64_i8(afR2, bf2, aR, 0, 0, 0);       \
    aZ = __builtin_amdgcn_mfma_i32_16x16x64_i8(afZ2, bf2, aZ, 0, 0, 0);       \
    aN = __builtin_amdgcn_mfma_i32_16x16x64_i8(afN2, bf2, aN, 0, 0, 0);       \
    int vR = aR[0], vZ = aZ[0], vN = aN[0];                                   \
    vR = __builtin_amdgcn_update_dpp(vR, aR[1], 0x114, 0xF, 0x2, false);      \
    vR = __builtin_amdgcn_update_dpp(vR, aR[2], 0x118, 0xF, 0x4, false);      \
    vR = __builtin_amdgcn_update_dpp(vR, aR[3], 0x11C, 0xF, 0x8, false);      \
    vZ = __builtin_amdgcn_update_dpp(vZ, aZ[1], 0x114, 0xF, 0x2, false);      \
    vZ = __builtin_amdgcn_update_dpp(vZ, aZ[2], 0x118, 0xF, 0x4, false);      \
    vZ = __builtin_amdgcn_update_dpp(vZ, aZ[3], 0x11C, 0xF, 0x8, false);      \
    vN = __builtin_amdgcn_update_dpp(vN, aN[1], 0x114, 0xF, 0x2, false);      \
    vN = __builtin_amdgcn_update_dpp(vN, aN[2], 0x118, 0xF, 0x4, false);      \
    vN = __builtin_amdgcn_update_dpp(vN, aN[3], 0x11C, 0xF, 0x8, false);      \
    float pR = fmaf((float)vR, dqR, baseR);                                   \
    float pZ = fmaf((float)vZ, dqZ, baseZ);                                   \
    float pN = fmaf((float)vN, dqN, baseN);                                   \
    float xv = x_s[b * XSTR + (t_)];                                          \
    float er = exp2_fast(fmaf(xv, wrS, pR));                                  \
    float ez = exp2hw(fminf(fmaf(xv, wzS, pZ), 14.0f));                       \
    float dR = 1.0f + er, dZ = 1.0f + ez;                                     \
    float qq = rcpf(dR * dZ);                                                 \
    float rr = qq * dZ, zz = qq * dR;                                         \
    float gn = fmaf(rr, pN, fmaf(xv, wnS, bnI));                              \
    float en = exp2hw(fminf(gn, 30.0f));                                      \
    float nn = fmaf(-2.0f, rcpf(1.0f + en), 1.0f);                            \
    h = fmaf(zz, h - nn, nn);                                                 \
    int hq = __float_as_int(fmaf(h, 127.0f, 12582912.0f));                    \
    *(char*)((wb) + wboff8) = (char)hq;                                       \
    LDS_BARRIER();                                                            \
} while (0)

    char* buf0 = hfr_s;
    char* buf1 = hfr_s + KT3 * FRAGB;
    for (int t = 0; t < T_LEN; t += 2) {
        STEP(buf0, buf1, t);
        STEP(buf1, buf0, t + 1);
    }
#undef STEP
#undef LDS_BARRIER

    // ---- final FC: publish h (f32) into x_s (x done), 40 lanes reduce ----
    __syncthreads();
    if (u < PST) x_s[b * PST + u] = h;
    __syncthreads();
    if (tid < BB * 10) {
        int bb = tid / 10, c = tid % 10;
        float acc = b_fc[c];
        for (int k = 0; k < H; ++k)
            acc = fmaf(x_s[bb * PST + k], w_fc[c * H + k], acc);
        out[(b0 + bb) * 10 + c] = acc;
    }
}

extern "C" void kernel_launch(void* const* d_in, const int* in_sizes, int n_in,
                              void* d_out, int out_size, void* d_ws, size_t ws_size,
                              hipStream_t stream) {
    const float* x    = (const float*)d_in[0];
    const float* w_ih = (const float*)d_in[1];
    const float* w_hh = (const float*)d_in[2];
    const float* b_ih = (const float*)d_in[3];
    const float* b_hh = (const float*)d_in[4];
    const float* w_fc = (const float*)d_in[5];
    const float* b_fc = (const float*)d_in[6];
    float* out = (float*)d_out;

    gru_i8<<<NBLK, NTHR, 0, stream>>>(x, w_ih, w_hh, b_ih, b_hh, w_fc, b_fc, out);
}